// Round 6
// baseline (581.129 us; speedup 1.0000x reference)
//
#include <hip/hip_runtime.h>

#define NN_F 500
#define HID 64
#define NC 40
#define SCAN_T 256
#define SCAN_E 8
#define SCAN_B (SCAN_T * SCAN_E)

typedef short s8v __attribute__((ext_vector_type(8)));
typedef float f4v __attribute__((ext_vector_type(4)));

__device__ __forceinline__ unsigned short rne_bf16(float x) {
    unsigned u = __float_as_uint(x);
    return (unsigned short)((u + 0x7fffu + ((u >> 16) & 1u)) >> 16);
}
__device__ __forceinline__ float bf16_lo(unsigned v) {   // low 16 bits as bf16
    return __uint_as_float(v << 16);
}
__device__ __forceinline__ float bf16_hi(unsigned v) {   // high 16 bits as bf16
    return __uint_as_float(v & 0xffff0000u);
}

// ---- edge_index may arrive as int32 (harness-converted) or raw int64. ----
__device__ __forceinline__ int load_edge(const void* ei, long long idx, int is64) {
    if (is64) return (int)((const long long*)ei)[idx];
    return ((const int*)ei)[idx];
}

// Per-block inline int64 detection: sample high words of first 256 int64 slots.
// Must be called by ALL threads of a 256-thread block.
__device__ __forceinline__ int detect_is64_block(const void* ei, int E) {
    const unsigned int* w = (const unsigned int*)ei;
    unsigned int acc = 0;
    int i = threadIdx.x;
    if (i < 256 && i < E) acc = w[2 * i + 1];
    int any = __any(acc != 0u);
    __shared__ int red[4];
    if ((threadIdx.x & 63) == 0) red[threadIdx.x >> 6] = any;
    __syncthreads();
    return (red[0] | red[1] | red[2] | red[3]) == 0;
}

// ---- deg histogram (+inline detect) with BOTH weight preps folded into grid tail ----
__global__ __launch_bounds__(256) void deg_wprep(const void* ei, int* __restrict__ deg,
                                                 const float* __restrict__ W1,
                                                 const float* __restrict__ W2,
                                                 unsigned short* __restrict__ Wt1,
                                                 unsigned short* __restrict__ Wt2,
                                                 int E, int degBlocks) {
    if ((int)blockIdx.x >= degBlocks) {
        int id = ((int)blockIdx.x - degBlocks) * 256 + threadIdx.x;
        if (id < 64 * 512) {
            int nn = id >> 9, k = id & 511;          // Wt1[64][512] from W1[500][64]
            Wt1[id] = rne_bf16(k < NN_F ? W1[k * HID + nn] : 0.f);
        } else {
            int id2 = id - 64 * 512;
            if (id2 < 64 * 64) {
                int nn = id2 >> 6, k = id2 & 63;     // Wt2[64][64] from W2[64][40]
                Wt2[id2] = rne_bf16(nn < NC ? W2[k * NC + nn] : 0.f);
            }
        }
        return;
    }
    int is64 = detect_is64_block(ei, E);
    long long e = (long long)blockIdx.x * 256 + threadIdx.x;
    if (e < E) {
        int d = load_edge(ei, (long long)E + e, is64);
        atomicAdd(&deg[d], 1);
    }
}

// ---- scan phase 1: per-block partial exclusive scan of deg; dinv fused ----
__global__ __launch_bounds__(SCAN_T) void scan1(const int* __restrict__ deg,
                                                int* __restrict__ off,
                                                int* __restrict__ bsums,
                                                float* __restrict__ dinv, int n) {
    __shared__ int lds[SCAN_T];
    int base = blockIdx.x * SCAN_B + threadIdx.x * SCAN_E;
    int v[SCAN_E];
    int local = 0;
#pragma unroll
    for (int k = 0; k < SCAN_E; ++k) {
        int i = base + k;
        v[k] = (i < n) ? deg[i] : 0;
        if (i < n) dinv[i] = rsqrtf((float)v[k] + 1.0f);
        local += v[k];
    }
    lds[threadIdx.x] = local;
    __syncthreads();
    for (int o = 1; o < SCAN_T; o <<= 1) {
        int t = (threadIdx.x >= o) ? lds[threadIdx.x - o] : 0;
        __syncthreads();
        lds[threadIdx.x] += t;
        __syncthreads();
    }
    int prefix = lds[threadIdx.x] - local;
    if (threadIdx.x == SCAN_T - 1) bsums[blockIdx.x] = lds[threadIdx.x];
    int run = prefix;
#pragma unroll
    for (int k = 0; k < SCAN_E; ++k) {
        if (base + k < n) { off[base + k] = run; run += v[k]; }
    }
}

// ---- merged scan phases 2+3 (nb <= 64) ----
__global__ __launch_bounds__(SCAN_T) void scan_fin(int* __restrict__ off,
                                                   int* __restrict__ cur,
                                                   const int* __restrict__ bsums,
                                                   int n, int nb) {
    const int lane = threadIdx.x & 63;
    int v = (lane < nb && lane < (int)blockIdx.x) ? bsums[lane] : 0;
#pragma unroll
    for (int o = 1; o < 64; o <<= 1) v += __shfl_xor(v, o);
    const int add = v;
    if ((int)blockIdx.x == nb - 1 && threadIdx.x == 0) off[n] = add + bsums[nb - 1];
    int base = blockIdx.x * SCAN_B + threadIdx.x * SCAN_E;
#pragma unroll
    for (int k = 0; k < SCAN_E; ++k) {
        int i = base + k;
        if (i < n) { int t = off[i] + add; off[i] = t; cur[i] = t; }
    }
}

// fallback path (nb > 64)
__global__ void scan2(int* bsums, int* off, int nb, int n) {
    if (threadIdx.x == 0 && blockIdx.x == 0) {
        int run = 0;
        for (int i = 0; i < nb; ++i) { int t = bsums[i]; bsums[i] = run; run += t; }
        off[n] = run;
    }
}
__global__ __launch_bounds__(SCAN_T) void scan3(int* __restrict__ off,
                                                int* __restrict__ cur,
                                                const int* __restrict__ bsums, int n) {
    int base = blockIdx.x * SCAN_B + threadIdx.x * SCAN_E;
    int add = bsums[blockIdx.x];
#pragma unroll
    for (int k = 0; k < SCAN_E; ++k) {
        int i = base + k;
        if (i < n) { int v = off[i] + add; off[i] = v; cur[i] = v; }
    }
}

// Scatter edges into CSR buckets by dst. Packed {src, weight_bits} single 8B store.
__global__ __launch_bounds__(256) void build_kernel(const void* ei,
                                                    const float* __restrict__ dinv,
                                                    int* __restrict__ cur,
                                                    int2* __restrict__ csr, int E) {
    int is64 = detect_is64_block(ei, E);
    long long e = (long long)blockIdx.x * 256 + threadIdx.x;
    if (e >= E) return;
    int s = load_edge(ei, e, is64);
    int d = load_edge(ei, (long long)E + e, is64);
    int pos = atomicAdd(&cur[d], 1);
    csr[pos] = make_int2(s, (int)__float_as_uint(dinv[s] * dinv[d]));
}

// ---- BARRIER-FREE MFMA GEMM: out[n x OUTW](bf16) = A[n x K] @ Wh^T ----
// Whole weight matrix (64 x KPAD bf16, <= 64 KB) staged to LDS ONCE in blocked
// layout [KPAD/8][64][8] (lane stride 16 B -> 2-way max bank aliasing, no pad).
// One __syncthreads total; the K-loop has NO barriers: each lane loads its own
// A-fragment straight from global and feeds MFMA. Compiler keeps many loads in
// flight across unrolled K-steps -> latency hidden by ILP + 16 waves/CU.
// 512 threads = 8 waves; each wave owns 32 rows; block = 256 rows.
template<int KPAD, bool ABF16, int OUTW>
__global__ __launch_bounds__(512, 4) void gemm_direct(const void* Av,
                                                      const unsigned short* __restrict__ Wh,
                                                      unsigned short* __restrict__ out,
                                                      int n, int K) {
    __shared__ unsigned short Bs[64 * KPAD];   // blocked: [(k/8)][col][k%8]
    // stage W: dst chunk d -> kblk = d/64, col = d%64 ; src = Wh[col*KPAD + kblk*8]
    for (int d = threadIdx.x; d < 64 * KPAD / 8; d += 512) {
        int kblk = d >> 6, col = d & 63;
        *(s8v*)&Bs[d * 8] = *(const s8v*)&Wh[col * KPAD + kblk * 8];
    }
    __syncthreads();

    const int t = threadIdx.x;
    const int wave = t >> 6, lane = t & 63, q = lane >> 4, nn = lane & 15;
    const int base = blockIdx.x * 256 + wave * 32;
    const int r0 = base + nn, r1 = base + 16 + nn;
    const long long lr0 = (r0 < n) ? r0 : (n - 1);
    const long long lr1 = (r1 < n) ? r1 : (n - 1);

    f4v acc[2][4];
#pragma unroll
    for (int mt = 0; mt < 2; ++mt)
#pragma unroll
        for (int ct = 0; ct < 4; ++ct) acc[mt][ct] = (f4v){0.f, 0.f, 0.f, 0.f};

#pragma unroll 4
    for (int k0 = 0; k0 < KPAD; k0 += 32) {
        const int kk = k0 + q * 8;
        s8v ah0, ah1;
        if (ABF16) {
            const unsigned short* A = (const unsigned short*)Av;
            ah0 = *(const s8v*)&A[lr0 * KPAD + kk];
            ah1 = *(const s8v*)&A[lr1 * KPAD + kk];
        } else {
            const float* A = (const float*)Av;
            if (kk + 8 <= K) {
                float4 a0 = *(const float4*)&A[lr0 * K + kk];
                float4 a1 = *(const float4*)&A[lr0 * K + kk + 4];
                float4 c0 = *(const float4*)&A[lr1 * K + kk];
                float4 c1 = *(const float4*)&A[lr1 * K + kk + 4];
                ah0[0] = (short)rne_bf16(a0.x); ah0[1] = (short)rne_bf16(a0.y);
                ah0[2] = (short)rne_bf16(a0.z); ah0[3] = (short)rne_bf16(a0.w);
                ah0[4] = (short)rne_bf16(a1.x); ah0[5] = (short)rne_bf16(a1.y);
                ah0[6] = (short)rne_bf16(a1.z); ah0[7] = (short)rne_bf16(a1.w);
                ah1[0] = (short)rne_bf16(c0.x); ah1[1] = (short)rne_bf16(c0.y);
                ah1[2] = (short)rne_bf16(c0.z); ah1[3] = (short)rne_bf16(c0.w);
                ah1[4] = (short)rne_bf16(c1.x); ah1[5] = (short)rne_bf16(c1.y);
                ah1[6] = (short)rne_bf16(c1.z); ah1[7] = (short)rne_bf16(c1.w);
            } else {
#pragma unroll
                for (int j = 0; j < 8; ++j) {
                    float v0 = (kk + j < K) ? A[lr0 * K + kk + j] : 0.f;
                    float v1 = (kk + j < K) ? A[lr1 * K + kk + j] : 0.f;
                    ah0[j] = (short)rne_bf16(v0);
                    ah1[j] = (short)rne_bf16(v1);
                }
            }
        }
        const int bbase = ((kk >> 3) * 64) * 8;   // block row (k/8), then col*8
#pragma unroll
        for (int ct = 0; ct < 4; ++ct) {
            const s8v bh = *(const s8v*)&Bs[bbase + (ct * 16 + nn) * 8];
            acc[0][ct] = __builtin_amdgcn_mfma_f32_16x16x32_bf16(ah0, bh, acc[0][ct], 0, 0, 0);
            acc[1][ct] = __builtin_amdgcn_mfma_f32_16x16x32_bf16(ah1, bh, acc[1][ct], 0, 0, 0);
        }
    }

    // epilogue: C/D layout col=lane&15, row=(lane>>4)*4+r; store bf16
#pragma unroll
    for (int mt = 0; mt < 2; ++mt)
#pragma unroll
        for (int ct = 0; ct < 4; ++ct) {
            int col = ct * 16 + nn;
            if (col < OUTW) {
#pragma unroll
                for (int r = 0; r < 4; ++r) {
                    int row = base + mt * 16 + q * 4 + r;
                    if (row < n) out[(long long)row * OUTW + col] = rne_bf16(acc[mt][ct][r]);
                }
            }
        }
}

#define FMA8(W, H)                                          \
    acc[0] = fmaf(W, bf16_lo((H).x), acc[0]);               \
    acc[1] = fmaf(W, bf16_hi((H).x), acc[1]);               \
    acc[2] = fmaf(W, bf16_lo((H).y), acc[2]);               \
    acc[3] = fmaf(W, bf16_hi((H).y), acc[3]);               \
    acc[4] = fmaf(W, bf16_lo((H).z), acc[4]);               \
    acc[5] = fmaf(W, bf16_hi((H).z), acc[5]);               \
    acc[6] = fmaf(W, bf16_lo((H).w), acc[6]);               \
    acc[7] = fmaf(W, bf16_hi((H).w), acc[7])

// Layer-1 gather: wave per node, 8 edge slots x 8-feature octets (16B uint4 rows).
// Output written directly as bf16.
__global__ __launch_bounds__(256) void gather_l1(const int2* __restrict__ csr,
                                                 const int* __restrict__ off,
                                                 const unsigned short* __restrict__ h,
                                                 const float* __restrict__ dinv,
                                                 const float* __restrict__ b,
                                                 unsigned short* __restrict__ relu1, int n) {
    const int lane = threadIdx.x & 63;
    const int g = lane >> 3, fl = lane & 7;
    const int node = __builtin_amdgcn_readfirstlane(blockIdx.x * 4 + (threadIdx.x >> 6));
    if (node >= n) return;
    const int start = off[node], end = off[node + 1];
    float acc[8];
#pragma unroll
    for (int k = 0; k < 8; ++k) acc[k] = 0.f;
    int j = start;
    for (; j + 16 <= end; j += 16) {
        int2 ea = csr[j + g];
        int2 eb = csr[j + 8 + g];
        uint4 ha = *(const uint4*)(h + (long long)ea.x * 64 + fl * 8);
        uint4 hb = *(const uint4*)(h + (long long)eb.x * 64 + fl * 8);
        float wa = __uint_as_float((unsigned)ea.y);
        float wb = __uint_as_float((unsigned)eb.y);
        FMA8(wa, ha);
        FMA8(wb, hb);
    }
    for (; j < end; j += 8) {
        int jj = j + g;
        int2 e = csr[jj < end ? jj : end - 1];
        float w = (jj < end) ? __uint_as_float((unsigned)e.y) : 0.f;
        uint4 hv = *(const uint4*)(h + (long long)e.x * 64 + fl * 8);
        FMA8(w, hv);
    }
#pragma unroll
    for (int k = 0; k < 8; ++k) {
        acc[k] += __shfl_xor(acc[k], 8);
        acc[k] += __shfl_xor(acc[k], 16);
        acc[k] += __shfl_xor(acc[k], 32);
    }
    if (g == 0) {
        float dv = dinv[node];
        float w = dv * dv;
        uint4 hn = *(const uint4*)(h + (long long)node * 64 + fl * 8);
        FMA8(w, hn);
        float4 b4a = ((const float4*)b)[fl * 2];
        float4 b4b = ((const float4*)b)[fl * 2 + 1];
        float o[8];
        o[0] = acc[0] + b4a.x; o[1] = acc[1] + b4a.y;
        o[2] = acc[2] + b4a.z; o[3] = acc[3] + b4a.w;
        o[4] = acc[4] + b4b.x; o[5] = acc[5] + b4b.y;
        o[6] = acc[6] + b4b.z; o[7] = acc[7] + b4b.w;
        s8v r;
#pragma unroll
        for (int k = 0; k < 8; ++k)
            r[k] = (short)rne_bf16(o[k] > 0.f ? o[k] : 0.f);
        *(s8v*)&relu1[(long long)node * 64 + fl * 8] = r;
    }
}

// Layer-2 gather over PACKED h2 (stride 40 shorts = 80 B). Only lanes fl<5 load.
// Fused bias + relu + log_softmax.
__global__ __launch_bounds__(256) void gather_l2(const int2* __restrict__ csr,
                                                 const int* __restrict__ off,
                                                 const unsigned short* __restrict__ h,
                                                 const float* __restrict__ dinv,
                                                 const float* __restrict__ b,
                                                 float* __restrict__ out, int n) {
    const int lane = threadIdx.x & 63;
    const int g = lane >> 3, fl = lane & 7;
    const int node = __builtin_amdgcn_readfirstlane(blockIdx.x * 4 + (threadIdx.x >> 6));
    if (node >= n) return;
    const int start = off[node], end = off[node + 1];
    float acc[8];
#pragma unroll
    for (int k = 0; k < 8; ++k) acc[k] = 0.f;
    int j = start;
    for (; j + 16 <= end; j += 16) {
        int2 ea = csr[j + g];
        int2 eb = csr[j + 8 + g];
        if (fl < 5) {
            uint4 ha = *(const uint4*)(h + (long long)ea.x * 40 + fl * 8);
            uint4 hb = *(const uint4*)(h + (long long)eb.x * 40 + fl * 8);
            float wa = __uint_as_float((unsigned)ea.y);
            float wb = __uint_as_float((unsigned)eb.y);
            FMA8(wa, ha);
            FMA8(wb, hb);
        }
    }
    for (; j < end; j += 8) {
        int jj = j + g;
        int2 e = csr[jj < end ? jj : end - 1];
        if (fl < 5) {
            float w = (jj < end) ? __uint_as_float((unsigned)e.y) : 0.f;
            uint4 hv = *(const uint4*)(h + (long long)e.x * 40 + fl * 8);
            FMA8(w, hv);
        }
    }
#pragma unroll
    for (int k = 0; k < 8; ++k) {
        acc[k] += __shfl_xor(acc[k], 8);
        acc[k] += __shfl_xor(acc[k], 16);
        acc[k] += __shfl_xor(acc[k], 32);
    }
    float v[8];
    float vmax = -1e30f;
    if (fl < 5) {
        float dv = dinv[node];
        float w = dv * dv;
        uint4 hn = *(const uint4*)(h + (long long)node * 40 + fl * 8);
        FMA8(w, hn);
        float4 b4a = ((const float4*)b)[fl * 2];
        float4 b4b = ((const float4*)b)[fl * 2 + 1];
        v[0] = acc[0] + b4a.x; v[1] = acc[1] + b4a.y;
        v[2] = acc[2] + b4a.z; v[3] = acc[3] + b4a.w;
        v[4] = acc[4] + b4b.x; v[5] = acc[5] + b4b.y;
        v[6] = acc[6] + b4b.z; v[7] = acc[7] + b4b.w;
#pragma unroll
        for (int k = 0; k < 8; ++k) {
            v[k] = v[k] > 0.f ? v[k] : 0.f;
            vmax = fmaxf(vmax, v[k]);
        }
    }
#pragma unroll
    for (int o = 1; o < 8; o <<= 1) vmax = fmaxf(vmax, __shfl_xor(vmax, o));
    float ssum = 0.f;
    if (fl < 5) {
#pragma unroll
        for (int k = 0; k < 8; ++k) ssum += expf(v[k] - vmax);
    }
#pragma unroll
    for (int o = 1; o < 8; o <<= 1) ssum += __shfl_xor(ssum, o);
    if (g == 0 && fl < 5) {
        float ls = vmax + logf(ssum);
        float4 o0 = make_float4(v[0] - ls, v[1] - ls, v[2] - ls, v[3] - ls);
        float4 o1 = make_float4(v[4] - ls, v[5] - ls, v[6] - ls, v[7] - ls);
        float4* dst = (float4*)(out + (long long)node * NC + fl * 8);
        dst[0] = o0;
        dst[1] = o1;
    }
}

static inline char* align256(char* p) {
    return (char*)(((uintptr_t)p + 255) & ~(uintptr_t)255);
}

extern "C" void kernel_launch(void* const* d_in, const int* in_sizes, int n_in,
                              void* d_out, int out_size, void* d_ws, size_t ws_size,
                              hipStream_t stream) {
    const float* x  = (const float*)d_in[0];
    const void*  ei = d_in[1];
    const float* W1 = (const float*)d_in[2];
    const float* b1 = (const float*)d_in[3];
    const float* W2 = (const float*)d_in[4];
    const float* b2 = (const float*)d_in[5];
    float* out = (float*)d_out;
    const int n = in_sizes[0] / NN_F;   // 100000
    const int E = in_sizes[1] / 2;      // 1600000
    const int nScanBlocks = (n + SCAN_B - 1) / SCAN_B;
    const int degBlocks = (E + 255) / 256;
    const int gBlocks = (n + 255) / 256;   // 256 rows per gemm block

    char* p = (char*)d_ws;
    int* deg  = (int*)p;                 p = align256(p + (size_t)n * sizeof(int));
    int* off  = (int*)p;                 p = align256(p + (size_t)(n + 1) * sizeof(int));
    int* cur  = (int*)p;                 p = align256(p + (size_t)n * sizeof(int));
    int* bsums = (int*)p;                p = align256(p + 256 * sizeof(int));
    float* dinv = (float*)p;             p = align256(p + (size_t)n * sizeof(float));
    int2* csr = (int2*)p;                p = align256(p + (size_t)E * sizeof(int2));
    unsigned short* Wt1 = (unsigned short*)p; p = align256(p + (size_t)64 * 512 * sizeof(short));
    unsigned short* Wt2 = (unsigned short*)p; p = align256(p + (size_t)64 * 64 * sizeof(short));
    unsigned short* h1 = (unsigned short*)p; p = align256(p + (size_t)n * 64 * sizeof(unsigned short));
    unsigned short* relu1 = (unsigned short*)p; p = align256(p + (size_t)n * 64 * sizeof(unsigned short));
    unsigned short* h2 = h1;  // reuse: h1 dead after gather_l1 (h2 is n*40 <= n*64)

    (void)hipMemsetAsync(deg, 0, (size_t)n * sizeof(int), stream);
    deg_wprep<<<degBlocks + 144, 256, 0, stream>>>(ei, deg, W1, W2, Wt1, Wt2, E, degBlocks);

    scan1<<<nScanBlocks, SCAN_T, 0, stream>>>(deg, off, bsums, dinv, n);
    if (nScanBlocks <= 64) {
        scan_fin<<<nScanBlocks, SCAN_T, 0, stream>>>(off, cur, bsums, n, nScanBlocks);
    } else {
        scan2<<<1, 64, 0, stream>>>(bsums, off, nScanBlocks, n);
        scan3<<<nScanBlocks, SCAN_T, 0, stream>>>(off, cur, bsums, n);
    }
    build_kernel<<<degBlocks, 256, 0, stream>>>(ei, dinv, cur, csr, E);

    gemm_direct<512, false, 64><<<gBlocks, 512, 0, stream>>>(x, Wt1, h1, n, NN_F);
    gather_l1<<<(n + 3) / 4, 256, 0, stream>>>(csr, off, h1, dinv, b1, relu1, n);
    gemm_direct<64, true, 40><<<gBlocks, 512, 0, stream>>>(relu1, Wt2, h2, n, HID);
    gather_l2<<<(n + 3) / 4, 256, 0, stream>>>(csr, off, h2, dinv, b2, out, n);
}